// Round 1
// 235.974 us; speedup vs baseline: 1.0970x; 1.0970x over previous
//
#include <hip/hip_runtime.h>

// snnTorch Leaky recurrence, reset='subtract':
//   mem_t = 0.95*mem_{t-1} + x_t - spk_{t-1};  spk_t = (mem_t > 1)
// N=8192 independent chains, T=4000 sequential.
//
// R8: quad-per-row cooperative streaming. R1-R7 post-mortems showed every
// lane-per-row structure pays ~200-330 cyc per 16B quantum because each
// float4 load instruction carries 64 divergent addresses (stride 16000B) =
// 64 cache-line segments the vmem pipe processes serially. Fix: 4 lanes per
// row. Lane 4r+j streams quanta q==j (mod 4) of row r, so one wave load =
// 16 rows x 64 CONTIGUOUS bytes (16 full-line segments, 4x fewer, 0 waste),
// and wave count rises 128->512 (2 blocks/CU). All 4 lanes recompute the
// serial chain redundantly (free: issue cost is per-wave-instruction); x
// values are spread quad-internally with v_mov_b32_dpp quad_perm broadcasts
// (pure VALU, no LDS). Ring of 8 float4/lane = 128-step flight per load.
//
// Numerics: exact reference rounding ((0.95*mem + x) - r) via __f*_rn, no
// fma contraction - verified absmax 0.0 in R1-R7. Spike bits accumulated as
// acc = fma(r, 2^sh, acc): r in {0,1}, shifts are powers of two, partial
// sums < 2^16 -> every fma is exact; cvt_u32 exact. Pack layout identical
// to R4-R7 (word = packgroup>>3, nibble = (packgroup&7)*4), expand kernel
// unchanged.

namespace {

constexpr int T_LEN = 4000;
constexpr int N_NEU = 8192;
constexpr int QROW  = 128;   // packed row stride in u32 (125 used)

__device__ __forceinline__ void stepf(float xv, float& mem, float& r,
                                      float& acc, float bit) {
    float t = __fmul_rn(0.95f, mem);
    t       = __fadd_rn(t, xv);
    mem     = __fsub_rn(t, r);      // r = spike_{t-1} = reset_t
    bool s  = mem > 1.0f;
    r   = s ? 1.0f : 0.0f;          // spike_t == reset_{t+1}
    acc = __fmaf_rn(r, bit, acc);   // exact: r in {0,1}, bit = 2^sh, acc < 2^16
}

// broadcast from lane (quad_base + J) to all 4 lanes of the quad (VALU dpp)
template<int J>
__device__ __forceinline__ float qb(float v) {
    return __int_as_float(
        __builtin_amdgcn_mov_dpp(__float_as_int(v), J * 0x55, 0xF, 0xF, true));
}
template<int J>
__device__ __forceinline__ float4 qb4(const float4 v) {
    float4 o;
    o.x = qb<J>(v.x); o.y = qb<J>(v.y); o.z = qb<J>(v.z); o.w = qb<J>(v.w);
    return o;
}

// One 16-step big-group from ring slot SLOT (quanta 4g+0..4g+3 held by quad
// lanes 0..3). Optionally refill SLOT with group g+8 (p points at group g&~7
// base for this lane). Returns the 16 spike bits.
template<int SLOT, bool REFILL>
__device__ __forceinline__ unsigned group16(const float* __restrict__ p,
                                            float4* __restrict__ ring,
                                            float& mem, float& r) {
    float4 a0 = qb4<0>(ring[SLOT]);   // steps 16g+0 .. +3
    float4 a1 = qb4<1>(ring[SLOT]);   // steps 16g+4 .. +7
    float4 a2 = qb4<2>(ring[SLOT]);   // steps 16g+8 .. +11
    float4 a3 = qb4<3>(ring[SLOT]);   // steps 16g+12.. +15
    if (REFILL)   // slot freed by the broadcasts above; 128-step flight
        ring[SLOT] = *reinterpret_cast<const float4*>(p + 128 + 16 * SLOT);
    float acc = 0.0f;
    stepf(a0.x, mem, r, acc, 1.f);      stepf(a0.y, mem, r, acc, 2.f);
    stepf(a0.z, mem, r, acc, 4.f);      stepf(a0.w, mem, r, acc, 8.f);
    stepf(a1.x, mem, r, acc, 16.f);     stepf(a1.y, mem, r, acc, 32.f);
    stepf(a1.z, mem, r, acc, 64.f);     stepf(a1.w, mem, r, acc, 128.f);
    stepf(a2.x, mem, r, acc, 256.f);    stepf(a2.y, mem, r, acc, 512.f);
    stepf(a2.z, mem, r, acc, 1024.f);   stepf(a2.w, mem, r, acc, 2048.f);
    stepf(a3.x, mem, r, acc, 4096.f);   stepf(a3.y, mem, r, acc, 8192.f);
    stepf(a3.z, mem, r, acc, 16384.f);  stepf(a3.w, mem, r, acc, 32768.f);
    __builtin_amdgcn_sched_barrier(0);  // keep refills inside their group
    return (unsigned)acc;               // exact integer < 2^16
}

__global__ __launch_bounds__(64, 1)
void snn_scan(const float* __restrict__ x, unsigned* __restrict__ q) {
    const int l    = threadIdx.x;
    const int j    = l & 3;                       // quad phase (quantum mod 4)
    const int n    = blockIdx.x * 16 + (l >> 2);  // this quad's neuron row
    const bool lead = (j == 0);

    // lane streams quanta 4g+j: float offset 16g + 4j  (64 B/row contiguous
    // per wave-instruction across the quad)
    const float* p = x + (size_t)n * T_LEN + 4 * j;
    unsigned* qn   = q + (size_t)n * QROW;

    float mem = 0.0f;   // mem_0 = 0
    float r   = 0.0f;   // reset_1 = H(0-1) = 0

    float4 ring[8];     // 32 VGPRs, all indices static
#pragma unroll
    for (int i = 0; i < 8; ++i)
        ring[i] = *reinterpret_cast<const float4*>(p + 16 * i);

    // Main: 30 iters x 8 groups = groups 0..239 (words 0..119), full refill.
#pragma unroll 1
    for (int k = 0; k < 30; ++k) {
        unsigned u0 = group16<0, true>(p, ring, mem, r);
        unsigned u1 = group16<1, true>(p, ring, mem, r);
        unsigned u2 = group16<2, true>(p, ring, mem, r);
        unsigned u3 = group16<3, true>(p, ring, mem, r);
        unsigned u4 = group16<4, true>(p, ring, mem, r);
        unsigned u5 = group16<5, true>(p, ring, mem, r);
        unsigned u6 = group16<6, true>(p, ring, mem, r);
        unsigned u7 = group16<7, true>(p, ring, mem, r);
        if (lead)
            *reinterpret_cast<uint4*>(qn) =
                make_uint4(u0 | (u1 << 16), u2 | (u3 << 16),
                           u4 | (u5 << 16), u6 | (u7 << 16));
        qn += 4;
        p  += 128;
    }
    // Iter 30: groups 240..247 (words 120..123); refill only groups 248,249.
    {
        unsigned u0 = group16<0, true >(p, ring, mem, r);
        unsigned u1 = group16<1, true >(p, ring, mem, r);
        unsigned u2 = group16<2, false>(p, ring, mem, r);
        unsigned u3 = group16<3, false>(p, ring, mem, r);
        unsigned u4 = group16<4, false>(p, ring, mem, r);
        unsigned u5 = group16<5, false>(p, ring, mem, r);
        unsigned u6 = group16<6, false>(p, ring, mem, r);
        unsigned u7 = group16<7, false>(p, ring, mem, r);
        if (lead)
            *reinterpret_cast<uint4*>(qn) =
                make_uint4(u0 | (u1 << 16), u2 | (u3 << 16),
                           u4 | (u5 << 16), u6 | (u7 << 16));
        qn += 4;
        p  += 128;
    }
    // Epilogue: groups 248,249 from slots 0,1 -> word 124.
    unsigned e0 = group16<0, false>(p, ring, mem, r);
    unsigned e1 = group16<1, false>(p, ring, mem, r);
    if (lead)
        qn[0] = e0 | (e1 << 16);
}

// Expand packed nibbles -> float spikes, fully coalesced float4 writes.
// 8192*1000 float4s = 32000 blocks x 256 threads exactly. (unchanged)
__global__ __launch_bounds__(256)
void snn_expand(const unsigned* __restrict__ q, float* __restrict__ out) {
    const unsigned i = blockIdx.x * 256 + threadIdx.x;  // float4 index
    const unsigned n = i / 1000u;                       // neuron row
    const unsigned c = i - n * 1000u;                   // float4 col
    const unsigned w = q[n * QROW + (c >> 3)];
    const unsigned nib = w >> ((c & 7u) * 4u);
    float4 f;
    f.x = (nib & 1u) ? 1.0f : 0.0f;
    f.y = (nib & 2u) ? 1.0f : 0.0f;
    f.z = (nib & 4u) ? 1.0f : 0.0f;
    f.w = (nib & 8u) ? 1.0f : 0.0f;
    reinterpret_cast<float4*>(out)[i] = f;
}

} // namespace

extern "C" void kernel_launch(void* const* d_in, const int* in_sizes, int n_in,
                              void* d_out, int out_size, void* d_ws, size_t ws_size,
                              hipStream_t stream) {
    const float* x = (const float*)d_in[0];
    float* out     = (float*)d_out;
    unsigned* q    = (unsigned*)d_ws;   // >= 4 MiB (verified R4-R7)
    snn_scan<<<dim3(N_NEU / 16), dim3(64), 0, stream>>>(x, q);
    snn_expand<<<dim3(32000), dim3(256), 0, stream>>>(q, out);
}